// Round 3
// baseline (2139.352 us; speedup 1.0000x reference)
//
#include <hip/hip_runtime.h>

#define H 181
#define T_LEN 1024
#define BB 16            // batch rows per block
#define NBLK 64          // 64 * 16 = 1024
#define NTHR 256         // 4 waves, 1 wave/SIMD
#define KT 6             // K tiles of 32 -> 192 >= 181
#define HBS 200          // h row stride in bf16 units (400 B: 16B-aligned rows)
#define JP 192           // padded hidden dim
#define NU 3             // j-tiles per wave (12 tiles / 4 waves)

typedef __attribute__((ext_vector_type(8))) short short8;
typedef __attribute__((ext_vector_type(4))) float floatx4;

__device__ __forceinline__ unsigned short f2bf(float f) {
    unsigned u = __float_as_uint(f);
    u += 0x7fff + ((u >> 16) & 1);          // RNE
    return (unsigned short)(u >> 16);
}
__device__ __forceinline__ float sigf(float v) { return 1.0f / (1.0f + __expf(-v)); }
__device__ __forceinline__ float tanh_fast(float v) {
    float e = __expf(2.0f * v);             // +inf -> 1, 0 -> -1
    return 1.0f - 2.0f / (e + 1.0f);
}

// 64 persistent blocks x 16 batch rows. 4 waves; wave wv owns j-tiles
// {3wv, 3wv+1, 3wv+2} (j = jt*16 + col) for all 3 gates: 9 MFMA n-tiles,
// B-frags + gate weights live in registers all 1024 steps. Gate biases are
// pre-seeded in the accumulators. Only h (bf16) round-trips through LDS.
__launch_bounds__(NTHR, 1)
__global__ void gru_mfma(const float* __restrict__ x,
                         const float* __restrict__ w_ih,
                         const float* __restrict__ w_hh,
                         const float* __restrict__ b_ih,
                         const float* __restrict__ b_hh,
                         const float* __restrict__ w_fc,
                         const float* __restrict__ b_fc,
                         float* __restrict__ out) {
    __shared__ __align__(16) unsigned short hbf_s[2][16 * HBS];  // dbuf h (bf16)
    __shared__ __align__(16) float x_s[T_LEN * 16];              // x^T [t][bb]
    __shared__ __align__(16) float hfin_s[16 * JP];              // final h for FC

    const int tid  = threadIdx.x;
    const int wv   = tid >> 6;
    const int lane = tid & 63;
    const int col  = lane & 15;
    const int q    = lane >> 4;
    const int b0   = blockIdx.x * BB;

    int  jj[NU];  bool jvv[NU];
    #pragma unroll
    for (int u = 0; u < NU; ++u) {
        jj[u]  = (3 * wv + u) * 16 + col;
        jvv[u] = (jj[u] < H);
    }

    // ---- B fragments (w_hh^T, bf16) in registers: [gate][u][kt] ----
    short8 bfr[3][NU][KT];
    #pragma unroll
    for (int i = 0; i < 3; ++i)
        #pragma unroll
        for (int u = 0; u < NU; ++u) {
            const int g = i * H + jj[u];
            #pragma unroll
            for (int kt = 0; kt < KT; ++kt) {
                short8 f;
                #pragma unroll
                for (int e = 0; e < 8; ++e) {
                    int k = kt * 32 + q * 8 + e;
                    float v = (jvv[u] && k < H) ? w_hh[g * H + k] : 0.0f;
                    f[e] = (short)f2bf(v);
                }
                bfr[i][u][kt] = f;
            }
        }

    // ---- per-lane gate weights / fused biases ----
    float wr[NU], wz[NU], wn[NU], brz[NU], bzz[NU], bin[NU], bhn[NU];
    #pragma unroll
    for (int u = 0; u < NU; ++u) {
        int j = jj[u];
        if (jvv[u]) {
            wr[u]  = w_ih[j]; wz[u] = w_ih[H + j]; wn[u] = w_ih[2 * H + j];
            brz[u] = b_ih[j] + b_hh[j];
            bzz[u] = b_ih[H + j] + b_hh[H + j];
            bin[u] = b_ih[2 * H + j];
            bhn[u] = b_hh[2 * H + j];
        } else {
            wr[u] = wz[u] = wn[u] = brz[u] = bzz[u] = bin[u] = bhn[u] = 0.0f;
        }
    }

    // ---- stage x coalesced: read [bb][t], write LDS [t][bb] ----
    for (int i = tid; i < BB * T_LEN; i += NTHR) {
        int bb = i >> 10, t = i & 1023;
        x_s[t * 16 + bb] = x[(size_t)b0 * T_LEN + i];
    }
    // zero both h buffers (pad cols [181,200) must stay 0 forever)
    for (int i = tid; i < 2 * 16 * HBS; i += NTHR) hbf_s[0][i] = 0;
    __syncthreads();

    float h[NU][4];
    #pragma unroll
    for (int u = 0; u < NU; ++u)
        #pragma unroll
        for (int r = 0; r < 4; ++r) h[u][r] = 0.0f;

    for (int t = 0; t < T_LEN; ++t) {
        const unsigned short* rb = hbf_s[t & 1];
        unsigned short*       wb = hbf_s[(t + 1) & 1];

        floatx4 xv = *(const floatx4*)&x_s[t * 16 + q * 4];   // batch q*4..q*4+3

        // A fragments once, reused by all 3 j-tile groups
        short8 a[KT];
        #pragma unroll
        for (int kt = 0; kt < KT; ++kt)
            a[kt] = *(const short8*)&rb[col * HBS + kt * 32 + q * 8];

        #pragma unroll
        for (int u = 0; u < NU; ++u) {
            floatx4 aR = {brz[u], brz[u], brz[u], brz[u]};
            floatx4 aZ = {bzz[u], bzz[u], bzz[u], bzz[u]};
            floatx4 aN = {bhn[u], bhn[u], bhn[u], bhn[u]};
            #pragma unroll
            for (int kt = 0; kt < KT; ++kt) {
                aR = __builtin_amdgcn_mfma_f32_16x16x32_bf16(a[kt], bfr[0][u][kt], aR, 0, 0, 0);
                aZ = __builtin_amdgcn_mfma_f32_16x16x32_bf16(a[kt], bfr[1][u][kt], aZ, 0, 0, 0);
                aN = __builtin_amdgcn_mfma_f32_16x16x32_bf16(a[kt], bfr[2][u][kt], aN, 0, 0, 0);
            }
            #pragma unroll
            for (int r = 0; r < 4; ++r) {
                float gr = fmaf(xv[r], wr[u], aR[r]);
                float gz = fmaf(xv[r], wz[u], aZ[r]);
                float rr = sigf(gr);
                float zz = sigf(gz);
                float nn = tanh_fast(fmaf(rr, aN[r], fmaf(xv[r], wn[u], bin[u])));
                h[u][r] = nn + zz * (h[u][r] - nn);
                if (jvv[u]) wb[(q * 4 + r) * HBS + jj[u]] = f2bf(h[u][r]);
            }
        }
        __syncthreads();
    }

    // ---- final FC via LDS ----
    #pragma unroll
    for (int u = 0; u < NU; ++u)
        if (jvv[u])
            #pragma unroll
            for (int r = 0; r < 4; ++r)
                hfin_s[(q * 4 + r) * JP + jj[u]] = h[u][r];
    __syncthreads();
    if (tid < BB * 10) {
        int bb = tid / 10, c = tid % 10;
        float acc = b_fc[c];
        for (int k = 0; k < H; ++k)
            acc = fmaf(hfin_s[bb * JP + k], w_fc[c * H + k], acc);
        out[(b0 + bb) * 10 + c] = acc;
    }
}

extern "C" void kernel_launch(void* const* d_in, const int* in_sizes, int n_in,
                              void* d_out, int out_size, void* d_ws, size_t ws_size,
                              hipStream_t stream) {
    const float* x    = (const float*)d_in[0];
    const float* w_ih = (const float*)d_in[1];
    const float* w_hh = (const float*)d_in[2];
    const float* b_ih = (const float*)d_in[3];
    const float* b_hh = (const float*)d_in[4];
    const float* w_fc = (const float*)d_in[5];
    const float* b_fc = (const float*)d_in[6];
    float* out = (float*)d_out;

    gru_mfma<<<NBLK, NTHR, 0, stream>>>(x, w_ih, w_hh, b_ih, b_hh, w_fc, b_fc, out);
}

// Round 4
// 964.535 us; speedup vs baseline: 2.2180x; 2.2180x over previous
//
#include <hip/hip_runtime.h>

#define H 181
#define T_LEN 1024
#define BB 16            // batch rows per block
#define NBLK 64          // 64 * 16 = 1024
#define NTHR 768         // 12 waves, 3 per SIMD
#define KT 6             // K tiles of 32 -> 192 >= 181
#define HBS 200          // h row stride (bf16 units); rows 16B-aligned
#define JP 192           // padded hidden dim
#define XST 1057         // x_s row stride (odd -> conflict-free)

typedef __attribute__((ext_vector_type(8))) short short8;
typedef __attribute__((ext_vector_type(4))) float floatx4;

#define LOG2E 1.4426950408889634f

__device__ __forceinline__ unsigned f2bf_u(float f) {
    unsigned u = __float_as_uint(f);
    return (u + 0x7fff + ((u >> 16) & 1)) >> 16;   // RNE, inputs finite
}
__device__ __forceinline__ float rcpf(float x) { return __builtin_amdgcn_rcpf(x); }
__device__ __forceinline__ float exp2f_hw(float x) { return __builtin_amdgcn_exp2f(x); }

// 64 persistent blocks x 16 batch rows, 12 waves (3/SIMD).
// Swapped MFMA roles: A = scaled w_hh (registers, m = unit), B = h (LDS,
// n = batch). Wave wv owns unit tile jt=wv for all 3 gates (18 MFMA/step).
// C lane (col,q) holds gates for units jt*16+q*4+{0..3}, batch col ->
// h-writeback is one packed ds_write_b64. log2e folded into weights; biases
// pre-seeded in accumulators; sigmoid/tanh via raw v_exp/v_rcp.
__launch_bounds__(NTHR, 3)
__global__ void gru_mfma(const float* __restrict__ x,
                         const float* __restrict__ w_ih,
                         const float* __restrict__ w_hh,
                         const float* __restrict__ b_ih,
                         const float* __restrict__ b_hh,
                         const float* __restrict__ w_fc,
                         const float* __restrict__ b_fc,
                         float* __restrict__ out) {
    __shared__ __align__(16) unsigned short hbf_s[2][16 * HBS];  // dbuf h bf16
    __shared__ __align__(16) float x_s[16 * XST];                // x [bb][t]
    __shared__ __align__(16) float hfin_s[16 * JP];              // final h

    const int tid  = threadIdx.x;
    const int wv   = tid >> 6;          // 0..11 = unit tile jt
    const int lane = tid & 63;
    const int col  = lane & 15;         // batch index (B-frag n / C col)
    const int q    = lane >> 4;
    const int b0   = blockIdx.x * BB;
    const int jt   = wv;

    // ---- A fragments: scaled w_hh, registers, [gate][kt] ----
    // A[m = jt*16+col][k = kt*32 + q*8 + e]
    const int  mu = jt * 16 + col;
    const bool mv = (mu < H);
    const float gscale[3] = {-LOG2E, -LOG2E, 2.0f * LOG2E};
    short8 afr[3][KT];
    #pragma unroll
    for (int g = 0; g < 3; ++g) {
        const float* wrow = w_hh + (size_t)(g * H + (mv ? mu : 0)) * H;
        #pragma unroll
        for (int kt = 0; kt < KT; ++kt) {
            short8 f;
            #pragma unroll
            for (int e = 0; e < 8; ++e) {
                int k = kt * 32 + q * 8 + e;
                float v = (mv && k < H) ? gscale[g] * wrow[k] : 0.0f;
                f[e] = (short)f2bf_u(v);
            }
            afr[g][kt] = f;
        }
    }

    // ---- per-lane unit params (4 consecutive units j0..j0+3), scaled ----
    const int j0 = jt * 16 + q * 4;
    float wrS[4], wzS[4], wnS[4], sR[4], sZ[4], sN[4], bnI[4];
    #pragma unroll
    for (int r = 0; r < 4; ++r) {
        int j = j0 + r;
        bool v = (j < H);
        wrS[r] = v ? -LOG2E * w_ih[j]             : 0.0f;
        wzS[r] = v ? -LOG2E * w_ih[H + j]         : 0.0f;
        wnS[r] = v ?  2.0f * LOG2E * w_ih[2*H + j]: 0.0f;
        sR[r]  = v ? -LOG2E * (b_ih[j] + b_hh[j]) : 0.0f;
        sZ[r]  = v ? -LOG2E * (b_ih[H+j] + b_hh[H+j]) : 0.0f;
        sN[r]  = v ?  2.0f * LOG2E * b_hh[2*H + j]: 0.0f;
        bnI[r] = v ?  2.0f * LOG2E * b_ih[2*H + j]: 0.0f;
    }

    // ---- stage x coalesced into [bb][t] (stride 1057: conflict-free) ----
    for (int i = tid; i < BB * T_LEN; i += NTHR) {
        int bb = i >> 10, t = i & 1023;
        x_s[bb * XST + t] = x[(size_t)b0 * T_LEN + i];
    }
    // zero both h buffers (pads [181,200) must stay 0)
    for (int i = tid; i < 2 * 16 * HBS; i += NTHR) hbf_s[0][i] = 0;
    __syncthreads();

    float h[4] = {0.f, 0.f, 0.f, 0.f};   // units j0+r, batch col

    for (int t = 0; t < T_LEN; ++t) {
        const unsigned short* rb = hbf_s[t & 1];
        unsigned short*       wb = hbf_s[(t + 1) & 1];

        float xv = x_s[col * XST + t];    // this lane's batch-col x_t

        short8 bfrg[KT];
        #pragma unroll
        for (int kt = 0; kt < KT; ++kt)
            bfrg[kt] = *(const short8*)&rb[col * HBS + kt * 32 + q * 8];

        floatx4 aR = {sR[0], sR[1], sR[2], sR[3]};
        floatx4 aZ = {sZ[0], sZ[1], sZ[2], sZ[3]};
        floatx4 aN = {sN[0], sN[1], sN[2], sN[3]};
        #pragma unroll
        for (int kt = 0; kt < KT; ++kt) {
            aR = __builtin_amdgcn_mfma_f32_16x16x32_bf16(afr[0][kt], bfrg[kt], aR, 0, 0, 0);
            aZ = __builtin_amdgcn_mfma_f32_16x16x32_bf16(afr[1][kt], bfrg[kt], aZ, 0, 0, 0);
            aN = __builtin_amdgcn_mfma_f32_16x16x32_bf16(afr[2][kt], bfrg[kt], aN, 0, 0, 0);
        }

        unsigned hp[4];
        #pragma unroll
        for (int r = 0; r < 4; ++r) {
            // r,z gates pre-scaled by -log2e: sigmoid = rcp(1 + 2^g)
            float rr = rcpf(1.0f + exp2f_hw(fmaf(xv, wrS[r], aR[r])));
            float zz = rcpf(1.0f + exp2f_hw(fmaf(xv, wzS[r], aZ[r])));
            // n gate pre-scaled by 2*log2e: tanh = 1 - 2*rcp(2^g + 1)
            float gn = fmaf(rr, aN[r], fmaf(xv, wnS[r], bnI[r]));
            float nn = fmaf(-2.0f, rcpf(exp2f_hw(gn) + 1.0f), 1.0f);
            h[r] = nn + zz * (h[r] - nn);
            hp[r] = f2bf_u(h[r]);
        }
        uint2 pk = make_uint2(hp[0] | (hp[1] << 16), hp[2] | (hp[3] << 16));
        *(uint2*)&wb[col * HBS + j0] = pk;   // one b64: units j0..j0+3, batch col

        __syncthreads();
    }

    // ---- final FC via LDS ----
    *(floatx4*)&hfin_s[col * JP + j0] = *(floatx4*)h;
    __syncthreads();
    if (tid < BB * 10) {
        int bb = tid / 10, c = tid % 10;
        float acc = b_fc[c];
        for (int k = 0; k < H; ++k)
            acc = fmaf(hfin_s[bb * JP + k], w_fc[c * H + k], acc);
        out[(b0 + bb) * 10 + c] = acc;
    }
}

extern "C" void kernel_launch(void* const* d_in, const int* in_sizes, int n_in,
                              void* d_out, int out_size, void* d_ws, size_t ws_size,
                              hipStream_t stream) {
    const float* x    = (const float*)d_in[0];
    const float* w_ih = (const float*)d_in[1];
    const float* w_hh = (const float*)d_in[2];
    const float* b_ih = (const float*)d_in[3];
    const float* b_hh = (const float*)d_in[4];
    const float* w_fc = (const float*)d_in[5];
    const float* b_fc = (const float*)d_in[6];
    float* out = (float*)d_out;

    gru_mfma<<<NBLK, NTHR, 0, stream>>>(x, w_ih, w_hh, b_ih, b_hh, w_fc, b_fc, out);
}

// Round 5
// 939.045 us; speedup vs baseline: 2.2782x; 1.0271x over previous
//
#include <hip/hip_runtime.h>

#define H 181
#define T_LEN 1024
#define BB 16            // batch rows per block
#define NBLK 64          // 64 * 16 = 1024
#define NTHR 768         // 12 waves, 3 per SIMD
#define KT 6             // K tiles of 32 -> 192 >= 181
#define FRAG 512         // shorts per kt fragment (64 lanes x 8)
#define JP 192           // padded hidden dim
#define XST 1057         // x_s row stride (odd -> conflict-free)

typedef __attribute__((ext_vector_type(8))) short short8;
typedef __attribute__((ext_vector_type(4))) float floatx4;

#define LOG2E 1.4426950408889634f

__device__ __forceinline__ unsigned f2bf_u(float f) {
    unsigned u = __float_as_uint(f);
    return (u + 0x7fff + ((u >> 16) & 1)) >> 16;   // RNE, inputs finite
}
__device__ __forceinline__ float rcpf(float x) { return __builtin_amdgcn_rcpf(x); }
__device__ __forceinline__ float exp2f_hw(float x) { return __builtin_amdgcn_exp2f(x); }

// 64 persistent blocks x 16 batch, 12 waves (3/SIMD).
// A = scaled w_hh (registers, m = unit), B = h (LDS, n = batch).
// h lives in LDS in EXACT MFMA B-fragment order: frag[kt][lane][e] with
// lane = q*16+col holding h[batch=col][k = kt*32+q*8+e]. Reads are the
// canonical lane*16 sequential pattern (conflict-free); the gate phase
// writes its 4 consecutive units straight into the frag slot (one b64).
// Pad units (181..191) may hold garbage: their A-weights are zero.
__launch_bounds__(NTHR, 3)
__global__ void gru_mfma(const float* __restrict__ x,
                         const float* __restrict__ w_ih,
                         const float* __restrict__ w_hh,
                         const float* __restrict__ b_ih,
                         const float* __restrict__ b_hh,
                         const float* __restrict__ w_fc,
                         const float* __restrict__ b_fc,
                         float* __restrict__ out) {
    __shared__ __align__(16) unsigned short hfr_s[2 * KT * FRAG];  // 24 KB dbuf
    __shared__ __align__(16) float x_s[16 * XST];                  // x [bb][t]; reused for FC

    const int tid  = threadIdx.x;
    const int wv   = tid >> 6;          // unit tile jt = wv (0..11)
    const int lane = tid & 63;
    const int col  = lane & 15;         // batch index
    const int q    = lane >> 4;
    const int b0   = blockIdx.x * BB;
    const int jt   = wv;

    // ---- A fragments: scaled w_hh in registers, [gate][kt] ----
    // A[m = jt*16+col][k = kt*32 + q*8 + e]; zero for m>=H or k>=H.
    const int  mu = jt * 16 + col;
    const bool mv = (mu < H);
    const float gscale[3] = {-LOG2E, -LOG2E, 2.0f * LOG2E};
    short8 afr[3][KT];
    #pragma unroll
    for (int g = 0; g < 3; ++g) {
        const float* wrow = w_hh + (size_t)(g * H + (mv ? mu : 0)) * H;
        #pragma unroll
        for (int kt = 0; kt < KT; ++kt) {
            short8 f;
            #pragma unroll
            for (int e = 0; e < 8; ++e) {
                int k = kt * 32 + q * 8 + e;
                float v = (mv && k < H) ? gscale[g] * wrow[k] : 0.0f;
                f[e] = (short)f2bf_u(v);
            }
            afr[g][kt] = f;
        }
    }

    // ---- per-lane unit params (units j0..j0+3), log2e pre-folded ----
    const int j0 = jt * 16 + q * 4;
    float wrS[4], wzS[4], wnS[4], bnI[4];
    floatx4 seedR, seedZ, seedN;
    #pragma unroll
    for (int r = 0; r < 4; ++r) {
        int j = j0 + r;
        bool v = (j < H);
        wrS[r]  = v ? -LOG2E * w_ih[j]              : 0.0f;
        wzS[r]  = v ? -LOG2E * w_ih[H + j]          : 0.0f;
        wnS[r]  = v ?  2.0f * LOG2E * w_ih[2*H + j] : 0.0f;
        bnI[r]  = v ?  2.0f * LOG2E * b_ih[2*H + j] : 0.0f;
        seedR[r] = v ? -LOG2E * (b_ih[j] + b_hh[j])         : 0.0f;
        seedZ[r] = v ? -LOG2E * (b_ih[H+j] + b_hh[H+j])     : 0.0f;
        seedN[r] = v ?  2.0f * LOG2E * b_hh[2*H + j]        : 0.0f;
    }

    // ---- frag-slot address for this lane's h write (units j0..j0+3, batch col) ----
    const int wkt  = j0 >> 5;
    const int wq   = (j0 >> 3) & 3;
    const int we   = j0 & 7;                                // 0 or 4
    const int woff = wkt * FRAG + (wq * 16 + col) * 8 + we; // shorts; 8B-aligned
    const int rbase = lane * 8;                             // shorts

    // ---- stage x coalesced into [bb][t] ----
    for (int i = tid; i < BB * T_LEN; i += NTHR) {
        int bb = i >> 10, t = i & 1023;
        x_s[bb * XST + t] = x[(size_t)b0 * T_LEN + i];
    }
    // zero both h frag buffers (h0 = 0)
    for (int i = tid; i < 2 * KT * FRAG; i += NTHR) hfr_s[i] = 0;
    __syncthreads();

    float h[4] = {0.f, 0.f, 0.f, 0.f};   // units j0+r, batch col

    auto step = [&](const unsigned short* rb, unsigned short* wb, int t) {
        float xv = x_s[col * XST + t];

        short8 bfrg[KT];
        #pragma unroll
        for (int kt = 0; kt < KT; ++kt)
            bfrg[kt] = *(const short8*)&rb[kt * FRAG + rbase];

        floatx4 aR = seedR, aZ = seedZ, aN = seedN;
        #pragma unroll
        for (int kt = 0; kt < KT; ++kt) {
            aR = __builtin_amdgcn_mfma_f32_16x16x32_bf16(afr[0][kt], bfrg[kt], aR, 0, 0, 0);
            aZ = __builtin_amdgcn_mfma_f32_16x16x32_bf16(afr[1][kt], bfrg[kt], aZ, 0, 0, 0);
            aN = __builtin_amdgcn_mfma_f32_16x16x32_bf16(afr[2][kt], bfrg[kt], aN, 0, 0, 0);
        }

        // gates: batched across r so the 4+4 exp2 / rcp pipeline
        float er[4], ez[4], rr[4], zz[4], en[4];
        #pragma unroll
        for (int r = 0; r < 4; ++r) er[r] = exp2f_hw(fmaf(xv, wrS[r], aR[r]));
        #pragma unroll
        for (int r = 0; r < 4; ++r) ez[r] = exp2f_hw(fmaf(xv, wzS[r], aZ[r]));
        #pragma unroll
        for (int r = 0; r < 4; ++r) rr[r] = rcpf(1.0f + er[r]);
        #pragma unroll
        for (int r = 0; r < 4; ++r) zz[r] = rcpf(1.0f + ez[r]);
        #pragma unroll
        for (int r = 0; r < 4; ++r)
            en[r] = exp2f_hw(fmaf(rr[r], aN[r], fmaf(xv, wnS[r], bnI[r])));
        unsigned hp[4];
        #pragma unroll
        for (int r = 0; r < 4; ++r) {
            float nn = fmaf(-2.0f, rcpf(en[r] + 1.0f), 1.0f);
            h[r] = nn + zz[r] * (h[r] - nn);
            hp[r] = f2bf_u(h[r]);
        }
        *(uint2*)&wb[woff] = make_uint2(hp[0] | (hp[1] << 16), hp[2] | (hp[3] << 16));
        __syncthreads();
    };

    for (int t = 0; t < T_LEN; t += 2) {
        step(hfr_s,             hfr_s + KT * FRAG, t);      // even: read buf0, write buf1
        step(hfr_s + KT * FRAG, hfr_s,             t + 1);  // odd:  read buf1, write buf0
    }

    // ---- final FC; reuse x_s as fp32 h buffer (x no longer needed) ----
    float* hfin = x_s;
    *(floatx4*)&hfin[col * JP + j0] = *(floatx4*)h;
    __syncthreads();
    if (tid < BB * 10) {
        int bb = tid / 10, c = tid % 10;
        float acc = b_fc[c];
        for (int k = 0; k < H; ++k)
            acc = fmaf(hfin[bb * JP + k], w_fc[c * H + k], acc);
        out[(b0 + bb) * 10 + c] = acc;
    }
}

extern "C" void kernel_launch(void* const* d_in, const int* in_sizes, int n_in,
                              void* d_out, int out_size, void* d_ws, size_t ws_size,
                              hipStream_t stream) {
    const float* x    = (const float*)d_in[0];
    const float* w_ih = (const float*)d_in[1];
    const float* w_hh = (const float*)d_in[2];
    const float* b_ih = (const float*)d_in[3];
    const float* b_hh = (const float*)d_in[4];
    const float* w_fc = (const float*)d_in[5];
    const float* b_fc = (const float*)d_in[6];
    float* out = (float*)d_out;

    gru_mfma<<<NBLK, NTHR, 0, stream>>>(x, w_ih, w_hh, b_ih, b_hh, w_fc, b_fc, out);
}